// Round 2
// baseline (488.746 us; speedup 1.0000x reference)
//
#include <hip/hip_runtime.h>
#include <hip/hip_bf16.h>

// Problem constants
#define BD   16
#define LQ   512
#define LK   4096
#define DM   128

typedef __attribute__((ext_vector_type(8))) short  short8;
typedef __attribute__((ext_vector_type(4))) float  f32x4;
typedef __attribute__((ext_vector_type(4))) int    i32x4;
typedef __attribute__((ext_vector_type(4))) unsigned short u16x4;

// ws layout in units of unsigned short (bf16 elements)
#define WQT_HI_S 0
#define WQT_LO_S 16384
#define WKT_HI_S 32768
#define WKT_LO_S 49152
#define QHI_S    65536
#define QLO_S    1114112
#define KHI_S    2162688
#define KLO_S    10551296
#define ROWSUM_S 18939904   // float[8192] lives here (byte offset 37,879,808)

static __device__ __forceinline__ unsigned short bf16_rne(float x) {
    union { float f; unsigned int u; } v; v.f = x;
    unsigned int u = v.u;
    u += 0x7FFFu + ((u >> 16) & 1u);   // round-to-nearest-even
    return (unsigned short)(u >> 16);
}
static __device__ __forceinline__ float bf16_f32(unsigned short h) {
    union { unsigned int u; float f; } v; v.u = ((unsigned int)h) << 16;
    return v.f;
}

// ---------------- kernel 1: transpose + hi/lo split of Wq, Wk; zero rowsum --
__global__ void setup_wt(const float* __restrict__ Wq, const float* __restrict__ Wk,
                         unsigned short* __restrict__ ws, float* __restrict__ rowsum) {
    int bx = blockIdx.x;                  // 64 blocks
    int mat = bx >> 5, chunk = bx & 31;
    const float* W = mat ? Wk : Wq;
    unsigned short* hi = ws + (mat ? WKT_HI_S : WQT_HI_S);
    unsigned short* lo = ws + (mat ? WKT_LO_S : WQT_LO_S);
    #pragma unroll
    for (int i = 0; i < 2; ++i) {
        int idx = chunk * 512 + i * 256 + threadIdx.x;   // 16384 per matrix
        int d = idx >> 7, e = idx & 127;
        float x = W[idx];                 // W[d][e]
        unsigned short h = bf16_rne(x);
        unsigned short l = bf16_rne(x - bf16_f32(h));
        hi[e * 128 + d] = h;              // WT[e][d]
        lo[e * 128 + d] = l;
    }
    int gtid = bx * 256 + threadIdx.x;
    if (gtid < BD * LQ) rowsum[gtid] = 0.0f;
}

// ---------------- kernel 2: projections q = query@Wq+bq, k = key@Wk+bk ------
__global__ __launch_bounds__(256) void proj_kernel(
        const float* __restrict__ query, const float* __restrict__ key,
        const float* __restrict__ bq, const float* __restrict__ bk,
        unsigned short* __restrict__ ws) {
    const int wave = threadIdx.x >> 6, lane = threadIdx.x & 63;
    const int r = lane & 15, g = lane >> 4;
    int rowtile = blockIdx.x * 4 + wave;   // 4608 tiles: 512 q + 4096 k

    const float* src; const float* bias;
    const unsigned short *wthi, *wtlo;
    unsigned short *ohi, *olo;
    int rowbase;
    if (rowtile < 512) {
        src = query; bias = bq;
        wthi = ws + WQT_HI_S; wtlo = ws + WQT_LO_S;
        ohi = ws + QHI_S; olo = ws + QLO_S;
        rowbase = rowtile * 16;
    } else {
        int kt = rowtile - 512;
        src = key; bias = bk;
        wthi = ws + WKT_HI_S; wtlo = ws + WKT_LO_S;
        ohi = ws + KHI_S; olo = ws + KLO_S;
        rowbase = kt * 16;
    }

    f32x4 acc[8];
    #pragma unroll
    for (int t = 0; t < 8; ++t) acc[t] = (f32x4){0.f, 0.f, 0.f, 0.f};

    const float* srow = src + (size_t)(rowbase + r) * DM + g * 8;
    #pragma unroll
    for (int s = 0; s < 4; ++s) {
        const f32x4* p = (const f32x4*)(srow + s * 32);
        f32x4 x0 = p[0];
        f32x4 x1 = p[1];
        short8 bh, bl;
        #pragma unroll
        for (int j = 0; j < 8; ++j) {
            float x = (j < 4) ? x0[j] : x1[j - 4];
            unsigned short h = bf16_rne(x);
            bh[j] = (short)h;
            bl[j] = (short)bf16_rne(x - bf16_f32(h));
        }
        #pragma unroll
        for (int t = 0; t < 8; ++t) {
            short8 ah = *(const short8*)(wthi + (t * 16 + r) * DM + s * 32 + g * 8);
            short8 al = *(const short8*)(wtlo + (t * 16 + r) * DM + s * 32 + g * 8);
            acc[t] = __builtin_amdgcn_mfma_f32_16x16x32_bf16(ah, bh, acc[t], 0, 0, 0);
            acc[t] = __builtin_amdgcn_mfma_f32_16x16x32_bf16(ah, bl, acc[t], 0, 0, 0);
            acc[t] = __builtin_amdgcn_mfma_f32_16x16x32_bf16(al, bh, acc[t], 0, 0, 0);
        }
    }

    #pragma unroll
    for (int t = 0; t < 8; ++t) {
        f32x4 bv = *(const f32x4*)(bias + t * 16 + g * 4);
        u16x4 hs, ls;
        #pragma unroll
        for (int rr = 0; rr < 4; ++rr) {
            float v = acc[t][rr] + bv[rr];
            unsigned short h = bf16_rne(v);
            hs[rr] = h;
            ls[rr] = bf16_rne(v - bf16_f32(h));
        }
        size_t o = (size_t)(rowbase + r) * DM + t * 16 + g * 4;
        *(u16x4*)(ohi + o) = hs;
        *(u16x4*)(olo + o) = ls;
    }
}

// ---------------- kernel 3: scores + tanh clip + mask + unnormalized exp ----
// No max pass needed: scores clipped to [-0.884, 0.884] -> exp always safe.
// Per wg (256 thr, 4 waves): (b, qt 16 q-rows, k-quarter); wave owns 256 k.
// One acc tile live at a time -> low VGPR -> high occupancy, streaming.
__global__ __launch_bounds__(256, 4) void score_kernel(
        const int* __restrict__ mask, float* __restrict__ out,
        const unsigned short* __restrict__ ws, float* __restrict__ rowsum) {
    int wg = blockIdx.x;                       // 2048
    int swz = (wg & 7) * 256 + (wg >> 3);      // bijective XCD swizzle
    int b = swz >> 7, kq = (swz >> 5) & 3, qt = swz & 31;
    const int wave = threadIdx.x >> 6, lane = threadIdx.x & 63;
    const int r = lane & 15, g = lane >> 4;
    const int kbase = kq * 1024 + wave * 256;

    const unsigned short* qhi = ws + QHI_S;
    const unsigned short* qlo = ws + QLO_S;
    const unsigned short* khi = ws + KHI_S;
    const unsigned short* klo = ws + KLO_S;

    const int qrow = qt * 16 + r;
    const size_t qoff = (size_t)(b * LQ + qrow) * DM + g * 8;
    short8 qh[4], ql[4];
    #pragma unroll
    for (int s = 0; s < 4; ++s) {
        qh[s] = *(const short8*)(qhi + qoff + s * 32);
        ql[s] = *(const short8*)(qlo + qoff + s * 32);
    }

    const unsigned short* khrow = khi + (size_t)(b * LK + kbase + r) * DM + g * 8;
    const unsigned short* klrow = klo + (size_t)(b * LK + kbase + r) * DM + g * 8;
    const int*  mrow = mask + (size_t)(b * LQ + qrow) * LK + kbase + g * 4;
    float*      orow = out  + (size_t)(b * LQ + qrow) * LK + kbase + g * 4;

    const float C1 = 0.8838834764831844f;      // 10 / sqrt(128)
    float psum = 0.f;
    #pragma unroll
    for (int t = 0; t < 16; ++t) {
        f32x4 acc = (f32x4){0.f, 0.f, 0.f, 0.f};
        const int off = t * 16 * DM;
        #pragma unroll
        for (int s = 0; s < 4; ++s) {
            short8 ah = *(const short8*)(khrow + off + s * 32);
            short8 al = *(const short8*)(klrow + off + s * 32);
            acc = __builtin_amdgcn_mfma_f32_16x16x32_bf16(ah, qh[s], acc, 0, 0, 0);
            acc = __builtin_amdgcn_mfma_f32_16x16x32_bf16(ah, ql[s], acc, 0, 0, 0);
            acc = __builtin_amdgcn_mfma_f32_16x16x32_bf16(al, qh[s], acc, 0, 0, 0);
        }
        i32x4 mv = __builtin_nontemporal_load((const i32x4*)(mrow + t * 16));
        f32x4 o;
        #pragma unroll
        for (int rr = 0; rr < 4; ++rr) {
            float x = acc[rr];
            float e = __expf(2.0f * fabsf(x));             // inf-safe tanh
            float th = 1.0f - 2.0f * __builtin_amdgcn_rcpf(e + 1.0f);
            float sp = C1 * copysignf(th, x);
            float p = __expf(sp);                          // sp in [-.884,.884]
            p = (mv[rr] != 0) ? p : 0.0f;
            o[rr] = p;
            psum += p;
        }
        *(f32x4*)(orow + t * 16) = o;   // regular store: keep L3-hot for norm
    }
    psum += __shfl_xor(psum, 16, 64);
    psum += __shfl_xor(psum, 32, 64);
    if (lane < 16) atomicAdd(rowsum + b * LQ + qrow, psum);
}

// ---------------- kernel 4: normalize out by row sums -----------------------
__global__ __launch_bounds__(256) void norm_kernel(float* __restrict__ out,
        const float* __restrict__ rowsum) {
    const int total4 = BD * LQ * (LK / 4);     // 8,388,608 f32x4
    f32x4* o4 = (f32x4*)out;
    int tid = blockIdx.x * 256 + threadIdx.x;  // 524,288 threads -> 16 iters
    #pragma unroll 4
    for (int i = tid; i < total4; i += 2048 * 256) {
        float s = rowsum[i >> 10];             // 1024 f32x4 per row; L2-hot
        f32x4 v = o4[i];
        float rinv = 1.0f / s;
        f32x4 o = (f32x4){v[0] * rinv, v[1] * rinv, v[2] * rinv, v[3] * rinv};
        __builtin_nontemporal_store(o, &o4[i]);
    }
}

extern "C" void kernel_launch(void* const* d_in, const int* in_sizes, int n_in,
                              void* d_out, int out_size, void* d_ws, size_t ws_size,
                              hipStream_t stream) {
    const float* query = (const float*)d_in[0];
    const float* key   = (const float*)d_in[1];
    const int*   mask  = (const int*)d_in[2];
    const float* Wq    = (const float*)d_in[3];
    const float* bq    = (const float*)d_in[4];
    const float* Wk    = (const float*)d_in[5];
    const float* bk    = (const float*)d_in[6];
    float* out = (float*)d_out;
    unsigned short* ws = (unsigned short*)d_ws;
    float* rowsum = (float*)(ws + ROWSUM_S);

    setup_wt<<<64, 256, 0, stream>>>(Wq, Wk, ws, rowsum);
    proj_kernel<<<(512 + 4096) / 4, 256, 0, stream>>>(query, key, bq, bk, ws);
    score_kernel<<<2048, 256, 0, stream>>>(mask, out, ws, rowsum);
    norm_kernel<<<2048, 256, 0, stream>>>(out, rowsum);
}

// Round 3
// 360.182 us; speedup vs baseline: 1.3569x; 1.3569x over previous
//
#include <hip/hip_runtime.h>

// Problem constants
#define BD   16
#define LQ   512
#define LK   4096
#define DM   128

typedef __attribute__((ext_vector_type(8))) short  short8;
typedef __attribute__((ext_vector_type(4))) float  f32x4;
typedef __attribute__((ext_vector_type(4))) int    i32x4;
typedef __attribute__((ext_vector_type(4))) unsigned short u16x4;

// ws layout in units of unsigned short (bf16 elements)
#define WQT_HI_S 0
#define WQT_LO_S 16384
#define WKT_HI_S 32768
#define WKT_LO_S 49152
#define QHI_S    65536
#define QLO_S    (QHI_S + BD * LQ * DM)      // 1,114,112
#define KHI_S    (QLO_S + BD * LQ * DM)      // 2,162,688
#define KLO_S    (KHI_S + BD * LK * DM)      // 10,551,296
#define ROWSUM_S (KLO_S + BD * LK * DM)      // 18,939,904 (floats live here)

static __device__ __forceinline__ unsigned short bf16_rne(float x) {
    union { float f; unsigned int u; } v; v.f = x;
    unsigned int u = v.u;
    u += 0x7FFFu + ((u >> 16) & 1u);
    return (unsigned short)(u >> 16);
}
static __device__ __forceinline__ float bf16_f32(unsigned short h) {
    union { unsigned int u; float f; } v; v.u = ((unsigned int)h) << 16;
    return v.f;
}

// Fragment-major offset for element (row, col) of a [R][128] bf16 plane,
// tiled in 16-row MFMA tiles. Reader (lane l = g*16+r, tile T, k-step s)
// sees offset T*2048 + s*512 + l*8 -> contiguous 1KB per (T,s) wave load.
static __device__ __forceinline__ int frag_off(int row, int col) {
    return ((row >> 4) << 11) + ((col >> 5) << 9) + (((col >> 3) & 3) << 7)
         + ((row & 15) << 3) + (col & 7);
}

// ---------------- kernel 1: Wq/Wk -> transposed, hi/lo, fragment-major ------
__global__ void setup_wt(const float* __restrict__ Wq, const float* __restrict__ Wk,
                         unsigned short* __restrict__ ws, float* __restrict__ rowsum) {
    int bx = blockIdx.x;                  // 64 blocks
    int mat = bx >> 5, chunk = bx & 31;
    const float* W = mat ? Wk : Wq;
    unsigned short* hi = ws + (mat ? WKT_HI_S : WQT_HI_S);
    unsigned short* lo = ws + (mat ? WKT_LO_S : WQT_LO_S);
    #pragma unroll
    for (int i = 0; i < 2; ++i) {
        int idx = chunk * 512 + i * 256 + threadIdx.x;   // 16384 per matrix
        int d = idx >> 7, e = idx & 127;
        float x = W[idx];                 // W[d][e]; wt plane is [e][d]
        unsigned short h = bf16_rne(x);
        unsigned short l = bf16_rne(x - bf16_f32(h));
        int off = frag_off(e, d);
        hi[off] = h;
        lo[off] = l;
    }
    int gtid = bx * 256 + threadIdx.x;
    if (gtid < BD * LQ) rowsum[gtid] = 0.0f;
}

// ---------------- kernel 2: projections, LDS-staged, fragment-major out -----
__global__ __launch_bounds__(256) void proj_kernel(
        const float* __restrict__ query, const float* __restrict__ key,
        const float* __restrict__ bq, const float* __restrict__ bk,
        unsigned short* __restrict__ ws) {
    __shared__ float tile[64 * 128];      // 32 KB, XOR-swizzled 32B granules
    const int tid = threadIdx.x;
    const int wave = tid >> 6, lane = tid & 63;
    const int r = lane & 15, g = lane >> 4;
    const int rt0 = blockIdx.x * 4;       // 1152 blocks x 4 rowtiles
    const bool isq = rt0 < 512;
    const float* src  = isq ? query : key;
    const float* bias = isq ? bq : bk;
    const unsigned short* wthi = ws + (isq ? WQT_HI_S : WKT_HI_S);
    const unsigned short* wtlo = ws + (isq ? WQT_LO_S : WKT_LO_S);
    unsigned short* ohi = ws + (isq ? QHI_S : KHI_S);
    unsigned short* olo = ws + (isq ? QLO_S : KLO_S);
    const int R0 = (isq ? rt0 : rt0 - 512) * 16;   // row base in q- or k-space

    {   // coalesced stage: 64 rows x 128 f32
        const f32x4* s4 = (const f32x4*)(src + (size_t)R0 * DM);
        char* tb = (char*)tile;
        #pragma unroll
        for (int u = 0; u < 8; ++u) {
            int idx = u * 256 + tid;
            int row = idx >> 5, c4 = idx & 31;
            int boff = (row << 9) + ((c4 << 4) ^ ((row & 7) << 5));
            *(f32x4*)(tb + boff) = s4[idx];
        }
    }
    __syncthreads();

    // build B fragments for this wave's 16 rows
    const int lrow = wave * 16 + r;
    short8 bh[4], bl[4];
    {
        const char* tb = (const char*)tile;
        const int xo = (lrow & 7) << 5;
        #pragma unroll
        for (int s = 0; s < 4; ++s) {
            int cb = (s << 7) + (g << 5);
            f32x4 x0 = *(const f32x4*)(tb + (lrow << 9) + (cb ^ xo));
            f32x4 x1 = *(const f32x4*)(tb + (lrow << 9) + ((cb ^ xo) + 16));
            #pragma unroll
            for (int j = 0; j < 8; ++j) {
                float x = (j < 4) ? x0[j] : x1[j - 4];
                unsigned short h = bf16_rne(x);
                bh[s][j] = (short)h;
                bl[s][j] = (short)bf16_rne(x - bf16_f32(h));
            }
        }
    }

    f32x4 acc[8];
    #pragma unroll
    for (int t = 0; t < 8; ++t) acc[t] = (f32x4){0.f, 0.f, 0.f, 0.f};

    #pragma unroll
    for (int s = 0; s < 4; ++s) {
        #pragma unroll
        for (int t = 0; t < 8; ++t) {
            short8 ah = *(const short8*)(wthi + t * 2048 + s * 512 + lane * 8);
            short8 al = *(const short8*)(wtlo + t * 2048 + s * 512 + lane * 8);
            acc[t] = __builtin_amdgcn_mfma_f32_16x16x32_bf16(ah, bh[s], acc[t], 0, 0, 0);
            acc[t] = __builtin_amdgcn_mfma_f32_16x16x32_bf16(ah, bl[s], acc[t], 0, 0, 0);
            acc[t] = __builtin_amdgcn_mfma_f32_16x16x32_bf16(al, bh[s], acc[t], 0, 0, 0);
        }
    }

    const int grow = R0 + lrow;
    const int b   = isq ? (grow >> 9)  : (grow >> 12);
    const int inb = isq ? (grow & 511) : (grow & 4095);
    unsigned short* hp = ohi + (size_t)b * (isq ? LQ * DM : LK * DM);
    unsigned short* lp = olo + (size_t)b * (isq ? LQ * DM : LK * DM);
    #pragma unroll
    for (int t = 0; t < 8; ++t) {
        int e0 = t * 16 + g * 4;
        f32x4 bv = *(const f32x4*)(bias + e0);
        u16x4 hs, ls;
        #pragma unroll
        for (int rr = 0; rr < 4; ++rr) {
            float v = acc[t][rr] + bv[rr];
            unsigned short h = bf16_rne(v);
            hs[rr] = h;
            ls[rr] = bf16_rne(v - bf16_f32(h));
        }
        int off = frag_off(inb, e0);
        *(u16x4*)(hp + off) = hs;
        *(u16x4*)(lp + off) = ls;
    }
}

// ---------------- kernel 3: scores + tanh clip + mask + unnormalized exp ----
// 1024 wgs x 256 thr. Block = (b, 32 q-rows, k-quarter); wave owns 256 k.
// k/q loads are fragment-contiguous 1KB streams; each k-load feeds 2 q-tiles.
__global__ __launch_bounds__(256, 3) void score_kernel(
        const int* __restrict__ mask, float* __restrict__ out,
        const unsigned short* __restrict__ ws, float* __restrict__ rowsum) {
    const int wg = blockIdx.x;                 // 1024
    const int swz = (wg & 7) * 128 + (wg >> 3);// XCD swizzle (1024 % 8 == 0)
    const int qt2 = swz & 15;
    const int pr  = swz >> 4;                  // (b,kq) pair: k-quarter L2-hot
    const int kq  = pr & 3;
    const int b   = pr >> 2;
    const int tid = threadIdx.x;
    const int wave = tid >> 6, lane = tid & 63;
    const int r = lane & 15, g = lane >> 4;
    const int kbase = kq * 1024 + wave * 256;

    const unsigned short* qhi = ws + QHI_S + b * (LQ * DM);
    const unsigned short* qlo = ws + QLO_S + b * (LQ * DM);
    const unsigned short* khi = ws + KHI_S + (size_t)b * (LK * DM);
    const unsigned short* klo = ws + KLO_S + (size_t)b * (LK * DM);

    short8 qh[2][4], ql[2][4];
    #pragma unroll
    for (int h = 0; h < 2; ++h) {
        #pragma unroll
        for (int s = 0; s < 4; ++s) {
            int off = (qt2 * 2 + h) * 2048 + s * 512 + lane * 8;
            qh[h][s] = *(const short8*)(qhi + off);
            ql[h][s] = *(const short8*)(qlo + off);
        }
    }

    const int qrow0 = qt2 * 32 + r;
    const size_t base0 = (size_t)(b * LQ + qrow0) * LK + kbase + g * 4;
    const int*  mrow0 = mask + base0;
    const int*  mrow1 = mrow0 + 16 * LK;
    float*      orow0 = out + base0;
    float*      orow1 = orow0 + 16 * LK;

    const float C1 = 0.8838834764831844f;      // 10 / sqrt(128)
    float ps0 = 0.f, ps1 = 0.f;

    #pragma unroll
    for (int TT = 0; TT < 4; ++TT) {
        i32x4 m0[4], m1[4];
        #pragma unroll
        for (int u = 0; u < 4; ++u) {          // prefetch 8 mask vectors
            m0[u] = __builtin_nontemporal_load((const i32x4*)(mrow0 + (TT * 4 + u) * 16));
            m1[u] = __builtin_nontemporal_load((const i32x4*)(mrow1 + (TT * 4 + u) * 16));
        }
        #pragma unroll
        for (int u = 0; u < 4; ++u) {
            const int T = kq * 64 + wave * 16 + TT * 4 + u;
            const unsigned short* khf = khi + T * 2048;
            const unsigned short* klf = klo + T * 2048;
            f32x4 a0 = (f32x4){0.f, 0.f, 0.f, 0.f};
            f32x4 a1 = (f32x4){0.f, 0.f, 0.f, 0.f};
            #pragma unroll
            for (int s = 0; s < 4; ++s) {
                short8 ah = *(const short8*)(khf + s * 512 + lane * 8);
                short8 al = *(const short8*)(klf + s * 512 + lane * 8);
                a0 = __builtin_amdgcn_mfma_f32_16x16x32_bf16(ah, qh[0][s], a0, 0, 0, 0);
                a1 = __builtin_amdgcn_mfma_f32_16x16x32_bf16(ah, qh[1][s], a1, 0, 0, 0);
                a0 = __builtin_amdgcn_mfma_f32_16x16x32_bf16(ah, ql[0][s], a0, 0, 0, 0);
                a1 = __builtin_amdgcn_mfma_f32_16x16x32_bf16(ah, ql[1][s], a1, 0, 0, 0);
                a0 = __builtin_amdgcn_mfma_f32_16x16x32_bf16(al, qh[0][s], a0, 0, 0, 0);
                a1 = __builtin_amdgcn_mfma_f32_16x16x32_bf16(al, qh[1][s], a1, 0, 0, 0);
            }
            f32x4 o0, o1;
            #pragma unroll
            for (int rr = 0; rr < 4; ++rr) {
                float x = a0[rr];
                float e = __expf(2.0f * fabsf(x));
                float th = 1.0f - 2.0f * __builtin_amdgcn_rcpf(e + 1.0f);
                float p = __expf(C1 * copysignf(th, x));
                p = (m0[u][rr] != 0) ? p : 0.0f;
                o0[rr] = p; ps0 += p;
                x = a1[rr];
                e = __expf(2.0f * fabsf(x));
                th = 1.0f - 2.0f * __builtin_amdgcn_rcpf(e + 1.0f);
                p = __expf(C1 * copysignf(th, x));
                p = (m1[u][rr] != 0) ? p : 0.0f;
                o1[rr] = p; ps1 += p;
            }
            *(f32x4*)(orow0 + (TT * 4 + u) * 16) = o0;   // regular: keep L3-hot
            *(f32x4*)(orow1 + (TT * 4 + u) * 16) = o1;
        }
    }

    ps0 += __shfl_xor(ps0, 16, 64); ps0 += __shfl_xor(ps0, 32, 64);
    ps1 += __shfl_xor(ps1, 16, 64); ps1 += __shfl_xor(ps1, 32, 64);
    __shared__ float rs[32];
    if (tid < 32) rs[tid] = 0.f;
    __syncthreads();
    if (lane < 16) { atomicAdd(&rs[r], ps0); atomicAdd(&rs[16 + r], ps1); }
    __syncthreads();
    if (tid < 32) atomicAdd(rowsum + b * LQ + qt2 * 32 + tid, rs[tid]);
}

// ---------------- kernel 4: normalize, one block per row --------------------
__global__ __launch_bounds__(256) void norm_kernel(float* __restrict__ out,
        const float* __restrict__ rowsum) {
    const int row = blockIdx.x;                // 8192
    const float rinv = 1.0f / rowsum[row];
    f32x4* o = (f32x4*)(out + (size_t)row * LK);
    #pragma unroll
    for (int u = 0; u < 4; ++u) {
        int i = u * 256 + threadIdx.x;
        f32x4 v = o[i];
        f32x4 w = (f32x4){v[0] * rinv, v[1] * rinv, v[2] * rinv, v[3] * rinv};
        __builtin_nontemporal_store(w, &o[i]);
    }
}

extern "C" void kernel_launch(void* const* d_in, const int* in_sizes, int n_in,
                              void* d_out, int out_size, void* d_ws, size_t ws_size,
                              hipStream_t stream) {
    const float* query = (const float*)d_in[0];
    const float* key   = (const float*)d_in[1];
    const int*   mask  = (const int*)d_in[2];
    const float* Wq    = (const float*)d_in[3];
    const float* bq    = (const float*)d_in[4];
    const float* Wk    = (const float*)d_in[5];
    const float* bk    = (const float*)d_in[6];
    float* out = (float*)d_out;
    unsigned short* ws = (unsigned short*)d_ws;
    float* rowsum = (float*)(ws + ROWSUM_S);

    setup_wt<<<64, 256, 0, stream>>>(Wq, Wk, ws, rowsum);
    proj_kernel<<<(512 + 4096) / 4, 256, 0, stream>>>(query, key, bq, bk, ws);
    score_kernel<<<1024, 256, 0, stream>>>(mask, out, ws, rowsum);
    norm_kernel<<<BD * LQ, 256, 0, stream>>>(out, rowsum);
}